// Round 4
// baseline (125.088 us; speedup 1.0000x reference)
//
#include <hip/hip_runtime.h>

// predict/target: fp32, shape (64, 3, 17, 4096)
// loss = sum((t-p)^2 * w[c]) / (bs*actionlen*seqlen),  w = {1, 1, 75825}
//
// Fused single-pass with DISTRIBUTED arrival counters:
//  - r1 post-mortem: __threadfence per block = L2 writeback storm -> 227 us.
//  - r2 post-mortem: single-address agent-scope arrival counter = 4352
//    serialized fabric RMWs (~45 us drain); memory phase itself ~17 us.
//  - r3 post-mortem: two-kernel structure pays ~20 us of dispatch/boundary
//    overhead (retire drain + gap + stage-2 launch); fused pays ~10.
//  - This version: fused kernel, but arrival distributed over 68 per-group
//    counters (64 blocks/group, 64 B apart -> parallel across channels) +
//    one 68-way global counter. Sync drain ~45 us -> ~1.5 us.
//  - 8 KiB memset zeroes the counter region each launch (ws re-poisoned).
//  - Memory phase: 4352 blocks = 17/CU balanced, ITERS=3 float4-pairs,
//    fully unrolled, one int division/thread (channel rotates (seg0+k)%3).
//  - Tail: last block reduces all 4352 partials with the EXACT round-2
//    double-accumulation order (proven absmax 0.0).

#define BLOCK_SIZE 256
#define ITERS 3
#define VEC_PER_CHAN 17408   // (17*4096)/4 : float4-groups per channel segment
#define W2 75825.0f          // MAXLEN
#define GROUP_SHIFT 6        // 64 blocks per arrival group
#define GROUP_SIZE (1 << GROUP_SHIFT)
#define CNT_STRIDE_U32 16    // 64 B spacing between counters (no line sharing)
#define PARTIAL_OFF 2048     // floats; counters live in ws[0..2048)
#define CNT_BYTES 8192       // bytes to memset (covers 68 group + 1 global cnt)

__device__ __forceinline__ float blockReduceF(float acc, float* smem) {
    #pragma unroll
    for (int off = 32; off > 0; off >>= 1)
        acc += __shfl_down(acc, off, 64);
    const int lane = threadIdx.x & 63;
    const int wid  = threadIdx.x >> 6;
    if (lane == 0) smem[wid] = acc;
    __syncthreads();
    float s = 0.0f;
    if (threadIdx.x == 0) {
        #pragma unroll
        for (int w = 0; w < BLOCK_SIZE / 64; ++w) s += smem[w];
    }
    return s;
}

// Exact fused kernel: nblocks*BLOCK_SIZE*ITERS == n4, nblocks % 64 == 0,
// stride == n4/3 == whole channel segments with (segments % 3) == 1.
__global__ __launch_bounds__(BLOCK_SIZE) void pm_mse_fused2(
    const float4* __restrict__ p, const float4* __restrict__ t,
    float* __restrict__ ws, float* __restrict__ out,
    int stride /* total threads = n4/3 */, int nblocks, float scale) {
    const int tid = blockIdx.x * BLOCK_SIZE + threadIdx.x;

    // Channel weight per k-step: (seg0 + k) % 3 (stride/VEC_PER_CHAN==64, 64%3==1)
    const int seg0 = tid / VEC_PER_CHAN;
    float w[ITERS];
    #pragma unroll
    for (int k = 0; k < ITERS; ++k)
        w[k] = (((seg0 + k) % 3) == 2) ? W2 : 1.0f;

    float4 a[ITERS], b[ITERS];
    #pragma unroll
    for (int k = 0; k < ITERS; ++k) {
        const int i = tid + k * stride;
        a[k] = p[i];
        b[k] = t[i];
    }
    float acc = 0.0f;
    #pragma unroll
    for (int k = 0; k < ITERS; ++k) {
        float dx = b[k].x - a[k].x;
        float dy = b[k].y - a[k].y;
        float dz = b[k].z - a[k].z;
        float dw = b[k].w - a[k].w;
        float s = dx * dx + dy * dy + dz * dz + dw * dw;
        acc += s * w[k];   // s*1.0f is bitwise s
    }

    __shared__ float smem[BLOCK_SIZE / 64];
    float s = blockReduceF(acc, smem);

    unsigned int* cnt = (unsigned int*)ws;
    float* partial = ws + PARTIAL_OFF;
    const int ngroups = nblocks >> GROUP_SHIFT;

    __shared__ bool amLast;
    if (threadIdx.x == 0) {
        amLast = false;
        // Publish partial: agent-scope store (write-through to coherent
        // point, NO L2 flush), then wait for THAT store's ack only.
        __hip_atomic_store(&partial[blockIdx.x], s,
                           __ATOMIC_RELAXED, __HIP_MEMORY_SCOPE_AGENT);
        asm volatile("s_waitcnt vmcnt(0)" ::: "memory");
        // Distributed arrival: per-group counter (64 RMWs each, groups in
        // parallel on distinct 64 B slots), then 68-way global counter.
        const unsigned g = (unsigned)blockIdx.x >> GROUP_SHIFT;
        const unsigned prev = __hip_atomic_fetch_add(
            &cnt[g * CNT_STRIDE_U32], 1u,
            __ATOMIC_RELAXED, __HIP_MEMORY_SCOPE_AGENT);
        if (prev == GROUP_SIZE - 1) {
            const unsigned p2 = __hip_atomic_fetch_add(
                &cnt[(unsigned)ngroups * CNT_STRIDE_U32], 1u,
                __ATOMIC_RELAXED, __HIP_MEMORY_SCOPE_AGENT);
            amLast = (p2 == (unsigned)(ngroups - 1));
        }
    }
    __syncthreads();
    if (!amLast) return;

    // All partials reached the coherent point before their counter bumps.
    // EXACT round-2 tail (proven absmax 0.0): strided double accumulate,
    // double shfl tree, double LDS combine.
    double dacc = 0.0;
    for (int i = threadIdx.x; i < nblocks; i += BLOCK_SIZE)
        dacc += (double)__hip_atomic_load(&partial[i],
                    __ATOMIC_RELAXED, __HIP_MEMORY_SCOPE_AGENT);
    #pragma unroll
    for (int off = 32; off > 0; off >>= 1)
        dacc += __shfl_down(dacc, off, 64);
    __shared__ double dsm[BLOCK_SIZE / 64];
    const int lane = threadIdx.x & 63;
    const int wid  = threadIdx.x >> 6;
    if (lane == 0) dsm[wid] = dacc;
    __syncthreads();
    if (threadIdx.x == 0) {
        double tot = 0.0;
        #pragma unroll
        for (int w = 0; w < BLOCK_SIZE / 64; ++w) tot += dsm[w];
        out[0] = (float)(tot * (double)scale);
    }
}

// ---- generic two-kernel fallback (any n4) ----
__global__ __launch_bounds__(BLOCK_SIZE) void pm_mse_partial_generic(
    const float4* __restrict__ p, const float4* __restrict__ t,
    float* __restrict__ partial, int n4) {
    float acc = 0.0f;
    const int stride = gridDim.x * blockDim.x;
    for (int i = blockIdx.x * blockDim.x + threadIdx.x; i < n4; i += stride) {
        float4 a = p[i];
        float4 b = t[i];
        float dx = b.x - a.x;
        float dy = b.y - a.y;
        float dz = b.z - a.z;
        float dw = b.w - a.w;
        float s = dx * dx + dy * dy + dz * dz + dw * dw;
        int c = (i / VEC_PER_CHAN) % 3;
        acc += (c == 2) ? s * W2 : s;
    }
    __shared__ float smem[BLOCK_SIZE / 64];
    float s = blockReduceF(acc, smem);
    if (threadIdx.x == 0) partial[blockIdx.x] = s;
}

__global__ __launch_bounds__(BLOCK_SIZE) void pm_mse_final(
    const float* __restrict__ partial, int nblocks, float* __restrict__ out,
    float scale) {
    double acc = 0.0;
    for (int i = threadIdx.x; i < nblocks; i += blockDim.x)
        acc += (double)partial[i];
    #pragma unroll
    for (int off = 32; off > 0; off >>= 1)
        acc += __shfl_down(acc, off, 64);
    __shared__ double smem[BLOCK_SIZE / 64];
    const int lane = threadIdx.x & 63;
    const int wid = threadIdx.x >> 6;
    if (lane == 0) smem[wid] = acc;
    __syncthreads();
    if (threadIdx.x == 0) {
        double s = 0.0;
        #pragma unroll
        for (int w = 0; w < BLOCK_SIZE / 64; ++w) s += smem[w];
        out[0] = (float)(s * (double)scale);
    }
}

extern "C" void kernel_launch(void* const* d_in, const int* in_sizes, int n_in,
                              void* d_out, int out_size, void* d_ws, size_t ws_size,
                              hipStream_t stream) {
    const float* predict = (const float*)d_in[0];
    const float* target  = (const float*)d_in[1];
    float* out = (float*)d_out;
    float* ws = (float*)d_ws;

    const int n = in_sizes[0];      // 64*3*17*4096 = 13,369,344 elements
    const int n4 = n / 4;           // 3,342,336 = 4352 * 256 * 3
    const float scale = 3.0f / (float)n;  // divisor = n / ddim

    const int chunk = BLOCK_SIZE * ITERS;   // 768
    const int blocks_exact = n4 / chunk;    // 4352 = 17 blocks/CU, 68 groups of 64
    const bool exact_ok =
        (n4 % chunk == 0) &&
        (blocks_exact % GROUP_SIZE == 0) &&
        ((n4 / ITERS) % VEC_PER_CHAN == 0) &&            // stride = whole segments
        (((n4 / ITERS) / VEC_PER_CHAN) % 3 == 1) &&       // rotation (seg0+k)%3 valid
        ((size_t)ws_size >= (size_t)(PARTIAL_OFF + blocks_exact) * 4);

    if (exact_ok) {
        const int stride = blocks_exact * BLOCK_SIZE;     // n4/3 = 1,114,112
        hipMemsetAsync(d_ws, 0, CNT_BYTES, stream);       // zero arrival counters
        pm_mse_fused2<<<blocks_exact, BLOCK_SIZE, 0, stream>>>(
            (const float4*)predict, (const float4*)target, ws, out,
            stride, blocks_exact, scale);
    } else {
        int blocks = (n4 + BLOCK_SIZE - 1) / BLOCK_SIZE;
        if (blocks > 2048) blocks = 2048;
        pm_mse_partial_generic<<<blocks, BLOCK_SIZE, 0, stream>>>(
            (const float4*)predict, (const float4*)target, ws + PARTIAL_OFF, n4);
        pm_mse_final<<<1, BLOCK_SIZE, 0, stream>>>(ws + PARTIAL_OFF, blocks, out, scale);
    }
}

// Round 6
// 121.294 us; speedup vs baseline: 1.0313x; 1.0313x over previous
//
#include <hip/hip_runtime.h>

// predict/target: fp32, shape (64, 3, 17, 4096)
// loss = sum((t-p)^2 * w[c]) / (bs*actionlen*seqlen),  w = {1, 1, 75825}
//
// Two-kernel structure (rounds 1-4 established: any in-kernel cross-block
// sync costs >= a second dispatch; totals invariant 122-125 across designs;
// residual anomaly = memory phase at ~3 TB/s vs 6.6 TB/s demonstrated).
//
// Round-4 post-mortem: VGPR_Count=20 despite a[3],b[3] source proves the
// compiler collapsed the load window to ~2-deep -> ~128 KB in flight per CU
// -> ~3 TB/s by Little's law. This version FORCES MLP:
//   Stage 1: 2048 blocks x 256 thr (8/CU), each thread issues ALL 12-14
//            global_load_dwordx4 (6 unconditional float4-pairs + 1 guarded)
//            before any FLOP, pinned with sched_barrier(0). ~340-390 KB in
//            flight per CU (~3x round 3). Plain partial store, no atomics.
//   Stage 2: single 256-thread block, 2048 partials (8/thread), double
//            accumulate in fixed order (proven absmax 0.0 tail).
//
// (Round-5 submission was identical; bench failed on container acquisition,
//  not on the kernel. Resubmitting unchanged to get the measurement.)

#define BLOCK_SIZE 256
#define PBLOCKS 2048         // 8 blocks/CU on 256 CUs
#define KMAX 6               // unconditional float4-pairs per thread
#define VEC_PER_CHAN 17408   // (17*4096)/4 : float4-groups per channel segment
#define W2 75825.0f          // MAXLEN

__device__ __forceinline__ float blockReduceF(float acc, float* smem) {
    #pragma unroll
    for (int off = 32; off > 0; off >>= 1)
        acc += __shfl_down(acc, off, 64);
    const int lane = threadIdx.x & 63;
    const int wid  = threadIdx.x >> 6;
    if (lane == 0) smem[wid] = acc;
    __syncthreads();
    float s = 0.0f;
    if (threadIdx.x == 0) {
        #pragma unroll
        for (int w = 0; w < BLOCK_SIZE / 64; ++w) s += smem[w];
    }
    return s;
}

__device__ __forceinline__ float wsq(const float4 a, const float4 b, int i) {
    const float dx = b.x - a.x;
    const float dy = b.y - a.y;
    const float dz = b.z - a.z;
    const float dw = b.w - a.w;
    const float s = dx * dx + dy * dy + dz * dz + dw * dw;
    return (((i / VEC_PER_CHAN) % 3) == 2) ? s * W2 : s;
}

// Exact kernel: requires KMAX*stride <= n4 <= (KMAX+1)*stride.
__global__ __launch_bounds__(BLOCK_SIZE) void pm_mse_partial_mlp(
    const float4* __restrict__ p, const float4* __restrict__ t,
    float* __restrict__ partial, int n4) {
    const int tid = blockIdx.x * BLOCK_SIZE + threadIdx.x;
    const int stride = PBLOCKS * BLOCK_SIZE;   // 524288

    // ---- issue ALL loads first (12-14 global_load_dwordx4 in flight) ----
    float4 a[KMAX + 1], b[KMAX + 1];
    #pragma unroll
    for (int k = 0; k < KMAX; ++k) {
        const int i = tid + k * stride;
        a[k] = p[i];
        b[k] = t[i];
    }
    const int itail = tid + KMAX * stride;
    const bool has_tail = (itail < n4);
    if (has_tail) { a[KMAX] = p[itail]; b[KMAX] = t[itail]; }
    // Pin: no FLOP may be hoisted above, no load may be sunk below.
    __builtin_amdgcn_sched_barrier(0);

    // ---- consume ----
    float acc = 0.0f;
    #pragma unroll
    for (int k = 0; k < KMAX; ++k)
        acc += wsq(a[k], b[k], tid + k * stride);
    if (has_tail)
        acc += wsq(a[KMAX], b[KMAX], itail);

    __shared__ float smem[BLOCK_SIZE / 64];
    const float s = blockReduceF(acc, smem);
    if (threadIdx.x == 0) partial[blockIdx.x] = s;
}

// ---- generic fallback (any n4) ----
__global__ __launch_bounds__(BLOCK_SIZE) void pm_mse_partial_generic(
    const float4* __restrict__ p, const float4* __restrict__ t,
    float* __restrict__ partial, int n4) {
    float acc = 0.0f;
    const int stride = gridDim.x * blockDim.x;
    for (int i = blockIdx.x * blockDim.x + threadIdx.x; i < n4; i += stride) {
        float4 a = p[i];
        float4 b = t[i];
        acc += wsq(a, b, i);
    }
    __shared__ float smem[BLOCK_SIZE / 64];
    float s = blockReduceF(acc, smem);
    if (threadIdx.x == 0) partial[blockIdx.x] = s;
}

__global__ __launch_bounds__(BLOCK_SIZE) void pm_mse_final(
    const float* __restrict__ partial, int nblocks, float* __restrict__ out,
    float scale) {
    double acc = 0.0;
    for (int i = threadIdx.x; i < nblocks; i += blockDim.x)
        acc += (double)partial[i];
    #pragma unroll
    for (int off = 32; off > 0; off >>= 1)
        acc += __shfl_down(acc, off, 64);
    __shared__ double smem[BLOCK_SIZE / 64];
    const int lane = threadIdx.x & 63;
    const int wid = threadIdx.x >> 6;
    if (lane == 0) smem[wid] = acc;
    __syncthreads();
    if (threadIdx.x == 0) {
        double s = 0.0;
        #pragma unroll
        for (int w = 0; w < BLOCK_SIZE / 64; ++w) s += smem[w];
        out[0] = (float)(s * (double)scale);
    }
}

extern "C" void kernel_launch(void* const* d_in, const int* in_sizes, int n_in,
                              void* d_out, int out_size, void* d_ws, size_t ws_size,
                              hipStream_t stream) {
    const float* predict = (const float*)d_in[0];
    const float* target  = (const float*)d_in[1];
    float* out = (float*)d_out;
    float* partial = (float*)d_ws;

    const int n = in_sizes[0];      // 64*3*17*4096 = 13,369,344 elements
    const int n4 = n / 4;           // 3,342,336 = 6*524288 + 196608
    const float scale = 3.0f / (float)n;  // divisor = n / ddim

    const int stride = PBLOCKS * BLOCK_SIZE;   // 524288
    const bool exact_ok =
        (n4 >= KMAX * stride) && (n4 <= (KMAX + 1) * stride) &&
        ((size_t)ws_size >= (size_t)PBLOCKS * 4);

    if (exact_ok) {
        pm_mse_partial_mlp<<<PBLOCKS, BLOCK_SIZE, 0, stream>>>(
            (const float4*)predict, (const float4*)target, partial, n4);
        pm_mse_final<<<1, BLOCK_SIZE, 0, stream>>>(partial, PBLOCKS, out, scale);
    } else {
        int blocks = (n4 + BLOCK_SIZE - 1) / BLOCK_SIZE;
        if (blocks > 2048) blocks = 2048;
        pm_mse_partial_generic<<<blocks, BLOCK_SIZE, 0, stream>>>(
            (const float4*)predict, (const float4*)target, partial, n4);
        pm_mse_final<<<1, BLOCK_SIZE, 0, stream>>>(partial, blocks, out, scale);
    }
}